// Round 1
// baseline (881.286 us; speedup 1.0000x reference)
//
#include <hip/hip_runtime.h>
#include <stddef.h>

// SpatialCGNL fp32 baseline.
// Pipeline: K0 zero accumulators -> K1 fused t/p/g conv + att partials
//           -> K2 GroupNorm stats over u=Wz*t (z never materialized)
//           -> K3 recompute u, apply att/stats/gamma/beta + residual.
// ws layout: t (16*256*4096 f32 = 64MB) | att (128 f32) | stats (256 f32)

#define B_   16
#define CIN_ 512
#define HW_  4096
#define CP_  256
#define G_   8
#define EPS_ 1e-5f

// ---------------- K0: zero att/stats accumulators ----------------
__global__ void k_zero(float* __restrict__ p, int n) {
  int i = blockIdx.x * blockDim.x + threadIdx.x;
  if (i < n) p[i] = 0.f;
}

// ---------------- K1: fused 1x1 convs t/p/g + att partial ----------------
// Tile: OT=64 (cp rows) x NT=64 (spatial cols), K chunk 32, 256 threads.
// Per thread: 4x4 frag x 3 matrices = 48 fp32 accumulators.
// W staged transposed Ws[kk][o] with LD=68 (keeps b128 reads 16B aligned:
// 272*kk + 16*ty bytes; 272 % 16 == 0).
#define OT 64
#define NT 64
#define KT 32
#define LDW 68

__global__ __launch_bounds__(256) void k_conv_tpg(
    const float* __restrict__ x,
    const float* __restrict__ Wt,
    const float* __restrict__ Wp,
    const float* __restrict__ Wg,
    float* __restrict__ tbuf,
    float* __restrict__ att)
{
  __shared__ float Xs[KT * LDW];
  __shared__ float Ws[3][KT * LDW];

  const int tid = threadIdx.x;
  const int o0 = blockIdx.x * OT;   // 0..192
  const int n0 = blockIdx.y * NT;   // 0..4032
  const int b  = blockIdx.z;

  const int tx = tid & 15;          // n fragment: n0 + tx*4
  const int ty = tid >> 4;          // o fragment: o0 + ty*4

  float acct[16], accp[16], accg[16];
#pragma unroll
  for (int i = 0; i < 16; i++) { acct[i] = 0.f; accp[i] = 0.f; accg[i] = 0.f; }

  // staging assignments
  const int wo  = tid >> 2;         // 0..63  (o row for W staging)
  const int wks = (tid & 3) * 8;    // k offset within chunk (0,8,16,24)
  const int xkk = tid >> 3;         // 0..31  (k row for X staging)
  const int xns = (tid & 7) * 8;    // n offset (0..56)

  const float* xb = x + (size_t)b * CIN_ * HW_;

  for (int k0 = 0; k0 < CIN_; k0 += KT) {
    // issue global loads first (overlap with previous iteration's compute)
    const float* xsrc = xb + (size_t)(k0 + xkk) * HW_ + n0 + xns;
    float4 xv0 = *(const float4*)xsrc;
    float4 xv1 = *(const float4*)(xsrc + 4);

    float4 wv[3][2];
    {
      const float* s0 = Wt + (size_t)(o0 + wo) * CIN_ + k0 + wks;
      const float* s1 = Wp + (size_t)(o0 + wo) * CIN_ + k0 + wks;
      const float* s2 = Wg + (size_t)(o0 + wo) * CIN_ + k0 + wks;
      wv[0][0] = *(const float4*)s0; wv[0][1] = *(const float4*)(s0 + 4);
      wv[1][0] = *(const float4*)s1; wv[1][1] = *(const float4*)(s1 + 4);
      wv[2][0] = *(const float4*)s2; wv[2][1] = *(const float4*)(s2 + 4);
    }

    __syncthreads();   // previous iteration done reading LDS
    *(float4*)&Xs[xkk * LDW + xns]     = xv0;
    *(float4*)&Xs[xkk * LDW + xns + 4] = xv1;
#pragma unroll
    for (int m = 0; m < 3; m++) {
      const float* w0 = (const float*)&wv[m][0];
      const float* w1 = (const float*)&wv[m][1];
#pragma unroll
      for (int j = 0; j < 4; j++) {
        Ws[m][(wks + j)     * LDW + wo] = w0[j];
        Ws[m][(wks + 4 + j) * LDW + wo] = w1[j];
      }
    }
    __syncthreads();

#pragma unroll 8
    for (int kk = 0; kk < KT; kk++) {
      float4 xa  = *(const float4*)&Xs[kk * LDW + tx * 4];
      float4 wt4 = *(const float4*)&Ws[0][kk * LDW + ty * 4];
      float4 wp4 = *(const float4*)&Ws[1][kk * LDW + ty * 4];
      float4 wg4 = *(const float4*)&Ws[2][kk * LDW + ty * 4];
      float xr[4]  = {xa.x, xa.y, xa.z, xa.w};
      float wtr[4] = {wt4.x, wt4.y, wt4.z, wt4.w};
      float wpr[4] = {wp4.x, wp4.y, wp4.z, wp4.w};
      float wgr[4] = {wg4.x, wg4.y, wg4.z, wg4.w};
#pragma unroll
      for (int i = 0; i < 4; i++) {
#pragma unroll
        for (int j = 0; j < 4; j++) {
          acct[i * 4 + j] = fmaf(wtr[i], xr[j], acct[i * 4 + j]);
          accp[i * 4 + j] = fmaf(wpr[i], xr[j], accp[i * 4 + j]);
          accg[i * 4 + j] = fmaf(wgr[i], xr[j], accg[i * 4 + j]);
        }
      }
    }
  }

  // store t tile (coalesced float4 per row)
#pragma unroll
  for (int i = 0; i < 4; i++) {
    const int row = o0 + ty * 4 + i;
    float4 v = make_float4(acct[i * 4 + 0], acct[i * 4 + 1],
                           acct[i * 4 + 2], acct[i * 4 + 3]);
    *(float4*)&tbuf[((size_t)b * CP_ + row) * HW_ + n0 + tx * 4] = v;
  }

  // att partial: sum p*g over this thread's 16 outputs.
  // Each wave's o-rows live in ONE cp-group: waves 0,1 -> group o0/32,
  // waves 2,3 -> o0/32+1.
  float attp = 0.f;
#pragma unroll
  for (int i = 0; i < 16; i++) attp = fmaf(accp[i], accg[i], attp);
#pragma unroll
  for (int off = 32; off > 0; off >>= 1) attp += __shfl_xor(attp, off);
  if ((tid & 63) == 0) {
    const int gidx = b * G_ + (o0 >> 5) + (tid >> 7);
    atomicAdd(&att[gidx], attp);
  }
}

// ---------------- K2: GroupNorm stats of u = Wz * t ----------------
// Grid (nt=8, g=8, b=16); 256 threads, 2 spatial cols/thread (512/block).
// u recomputed on the fly; only sum(u), sum(u^2) accumulated.
__global__ __launch_bounds__(256) void k_stats(
    const float* __restrict__ tbuf,
    const float* __restrict__ Wz,
    float* __restrict__ stats)
{
  __shared__ float wzs[64 * 32];
  __shared__ float red[8];
  const int tid = threadIdx.x;
  const int n0 = blockIdx.x * 512;
  const int g  = blockIdx.y;
  const int b  = blockIdx.z;

  const float4* wsrc = (const float4*)(Wz + (size_t)g * 2048);
  ((float4*)wzs)[tid]       = wsrc[tid];
  ((float4*)wzs)[tid + 256] = wsrc[tid + 256];
  __syncthreads();

  float2 tv[32];
  const float* tb = tbuf + ((size_t)b * CP_ + g * 32) * HW_ + n0 + tid * 2;
#pragma unroll
  for (int c = 0; c < 32; c++) tv[c] = *(const float2*)(tb + (size_t)c * HW_);

  float s1 = 0.f, s2 = 0.f;
#pragma unroll 4
  for (int o = 0; o < 64; o++) {
    float ux = 0.f, uy = 0.f;
#pragma unroll
    for (int c4 = 0; c4 < 8; c4++) {
      float4 w = *(const float4*)&wzs[o * 32 + c4 * 4];
      ux = fmaf(w.x, tv[c4 * 4 + 0].x, ux); uy = fmaf(w.x, tv[c4 * 4 + 0].y, uy);
      ux = fmaf(w.y, tv[c4 * 4 + 1].x, ux); uy = fmaf(w.y, tv[c4 * 4 + 1].y, uy);
      ux = fmaf(w.z, tv[c4 * 4 + 2].x, ux); uy = fmaf(w.z, tv[c4 * 4 + 2].y, uy);
      ux = fmaf(w.w, tv[c4 * 4 + 3].x, ux); uy = fmaf(w.w, tv[c4 * 4 + 3].y, uy);
    }
    s1 += ux + uy;
    s2 = fmaf(ux, ux, s2);
    s2 = fmaf(uy, uy, s2);
  }
#pragma unroll
  for (int off = 32; off > 0; off >>= 1) {
    s1 += __shfl_xor(s1, off);
    s2 += __shfl_xor(s2, off);
  }
  if ((tid & 63) == 0) { red[(tid >> 6) * 2] = s1; red[(tid >> 6) * 2 + 1] = s2; }
  __syncthreads();
  if (tid == 0) {
    float a = red[0] + red[2] + red[4] + red[6];
    float c = red[1] + red[3] + red[5] + red[7];
    atomicAdd(&stats[(b * G_ + g) * 2 + 0], a);
    atomicAdd(&stats[(b * G_ + g) * 2 + 1], c);
  }
}

// ---------------- K3: recompute u, apply att + GroupNorm + residual ----------------
// zn = (att*u - att*mu_u) * rsqrt(att^2*var_u + eps) = (u - mu)*sc,
// sc = att*rsqrt(att^2*var + eps). out = zn*gamma[c] + beta[c] + x.
__global__ __launch_bounds__(256) void k_out(
    const float* __restrict__ tbuf,
    const float* __restrict__ Wz,
    const float* __restrict__ x,
    const float* __restrict__ gamma,
    const float* __restrict__ beta,
    const float* __restrict__ att,
    const float* __restrict__ stats,
    float* __restrict__ out)
{
  __shared__ float wzs[64 * 32];
  const int tid = threadIdx.x;
  const int n0 = blockIdx.x * 512;
  const int g  = blockIdx.y;
  const int b  = blockIdx.z;

  const float4* wsrc = (const float4*)(Wz + (size_t)g * 2048);
  ((float4*)wzs)[tid]       = wsrc[tid];
  ((float4*)wzs)[tid + 256] = wsrc[tid + 256];
  __syncthreads();

  float2 tv[32];
  const float* tb = tbuf + ((size_t)b * CP_ + g * 32) * HW_ + n0 + tid * 2;
#pragma unroll
  for (int c = 0; c < 32; c++) tv[c] = *(const float2*)(tb + (size_t)c * HW_);

  const float attv = att[b * G_ + g];
  const float invN = 1.f / (64.f * 4096.f);
  const float S1 = stats[(b * G_ + g) * 2 + 0];
  const float S2 = stats[(b * G_ + g) * 2 + 1];
  const float mu  = S1 * invN;
  const float var = S2 * invN - mu * mu;
  const float sc  = attv * rsqrtf(attv * attv * var + EPS_);

#pragma unroll 4
  for (int o = 0; o < 64; o++) {
    float ux = 0.f, uy = 0.f;
#pragma unroll
    for (int c4 = 0; c4 < 8; c4++) {
      float4 w = *(const float4*)&wzs[o * 32 + c4 * 4];
      ux = fmaf(w.x, tv[c4 * 4 + 0].x, ux); uy = fmaf(w.x, tv[c4 * 4 + 0].y, uy);
      ux = fmaf(w.y, tv[c4 * 4 + 1].x, ux); uy = fmaf(w.y, tv[c4 * 4 + 1].y, uy);
      ux = fmaf(w.z, tv[c4 * 4 + 2].x, ux); uy = fmaf(w.z, tv[c4 * 4 + 2].y, uy);
      ux = fmaf(w.w, tv[c4 * 4 + 3].x, ux); uy = fmaf(w.w, tv[c4 * 4 + 3].y, uy);
    }
    const int c = g * 64 + o;
    const float gm = gamma[c];
    const float bt = beta[c];
    const size_t off = ((size_t)b * CIN_ + c) * HW_ + n0 + tid * 2;
    float2 xv = *(const float2*)(x + off);
    float2 ov;
    ov.x = fmaf((ux - mu) * sc, gm, bt + xv.x);
    ov.y = fmaf((uy - mu) * sc, gm, bt + xv.y);
    *(float2*)(out + off) = ov;
  }
}

extern "C" void kernel_launch(void* const* d_in, const int* in_sizes, int n_in,
                              void* d_out, int out_size, void* d_ws, size_t ws_size,
                              hipStream_t stream)
{
  const float* x     = (const float*)d_in[0];
  const float* Wt    = (const float*)d_in[1];
  const float* Wp    = (const float*)d_in[2];
  const float* Wg    = (const float*)d_in[3];
  const float* Wz    = (const float*)d_in[4];
  const float* gamma = (const float*)d_in[5];
  const float* beta  = (const float*)d_in[6];
  float* out = (float*)d_out;

  float* tbuf  = (float*)d_ws;                       // 16*256*4096 f32 = 64 MiB
  float* att   = tbuf + (size_t)B_ * CP_ * HW_;      // 128 f32
  float* stats = att + B_ * G_;                      // 256 f32

  k_zero<<<1, 384, 0, stream>>>(att, 384);

  dim3 g1(CP_ / OT, HW_ / NT, B_);                   // (4, 64, 16)
  k_conv_tpg<<<g1, 256, 0, stream>>>(x, Wt, Wp, Wg, tbuf, att);

  dim3 g2(HW_ / 512, G_, B_);                        // (8, 8, 16)
  k_stats<<<g2, 256, 0, stream>>>(tbuf, Wz, stats);
  k_out<<<g2, 256, 0, stream>>>(tbuf, Wz, x, gamma, beta, att, stats, out);
}

// Round 4
// 456.487 us; speedup vs baseline: 1.9306x; 1.9306x over previous
//
#include <hip/hip_runtime.h>
#include <stddef.h>
#include <stdint.h>

#define B_   16
#define CIN_ 512
#define HW_  4096
#define CP_  256
#define G_   8
#define EPS_ 1e-5f

typedef _Float16 f16;
typedef _Float16 f16x8 __attribute__((ext_vector_type(8)));
typedef _Float16 f16x2 __attribute__((ext_vector_type(2)));
typedef float    f32x4 __attribute__((ext_vector_type(4)));

// ---- workspace layout (bytes), all 16B aligned; total 49.0 MiB < 64 MiB known-good
#define OFF_WALL   0u          // W_all f16 [768][512]          = 786432 B
#define OFF_WZH    786432u     // Wzh  f16 [8][64][32]          =  32768 B
#define OFF_ATT    819200u     // att  f32 [128]                =    512 B
#define OFF_STATS  819712u     // stats f32 [256]               =   1024 B
#define OFF_T      1048576u    // t_t  f16 [16][4096][256]      = 33554432 B
#define OFF_XH     34603008u   // xh   f16 [4][4096][512] chunk = 16777216 B

#if defined(__has_builtin)
#if __has_builtin(__builtin_amdgcn_fdot2)
#define HAVE_FDOT2 1
#endif
#endif

__device__ __forceinline__ float dot2acc(f16x2 a, f16x2 b, float c) {
#ifdef HAVE_FDOT2
  return __builtin_amdgcn_fdot2(a, b, c, false);
#else
  return fmaf((float)a[0], (float)b[0], fmaf((float)a[1], (float)b[1], c));
#endif
}

// ---------------- K0: build W_all (t rows plain, p/g rows interleaved),
// Wzh f16, zero att+stats ----------------
__global__ __launch_bounds__(256) void k_prep0(
    const float* __restrict__ Wt, const float* __restrict__ Wp,
    const float* __restrict__ Wg, const float* __restrict__ Wz,
    char* __restrict__ ws)
{
  f16*   wall  = (f16*)(ws + OFF_WALL);
  f16*   wzh   = (f16*)(ws + OFF_WZH);
  float* att   = (float*)(ws + OFF_ATT);
  int idx = blockIdx.x * 256 + threadIdx.x;
  if (idx < 768 * 512) {
    int r = idx >> 9, k = idx & 511;
    float v;
    if (r < 256) v = Wt[r * 512 + k];
    else {
      int q = r - 256, o = q >> 1;
      v = (q & 1) ? Wg[o * 512 + k] : Wp[o * 512 + k];
    }
    wall[idx] = (f16)v;
  } else if (idx < 768 * 512 + 16384) {
    int i = idx - 768 * 512;
    wzh[i] = (f16)Wz[i];
  } else if (idx < 768 * 512 + 16384 + 384) {
    att[idx - (768 * 512 + 16384)] = 0.f;   // covers att(128) + stats(256)
  }
}

// ---------------- K_xpose: x[b][c][hw] f32 -> xh[b][hw][c] f16 (one 4-batch chunk) ----------------
__global__ __launch_bounds__(256) void k_xpose(const float* __restrict__ x,
                                               f16* __restrict__ xh)
{
  __shared__ f16 T[64][72];
  const int tid = threadIdx.x;
  const int c0  = blockIdx.x * 64;
  const int hw0 = blockIdx.y * 64;
  const int b   = blockIdx.z;

  const int cr  = (tid >> 4) * 4;       // 0..60, 4 consecutive c rows
  const int hwr = (tid & 15) * 4;       // 0..60
  const float* xb = x + ((size_t)b * CIN_ + c0) * HW_ + hw0;

  float4 v[4];
#pragma unroll
  for (int j = 0; j < 4; j++)
    v[j] = *(const float4*)(xb + (size_t)(cr + j) * HW_ + hwr);

#pragma unroll
  for (int i = 0; i < 4; i++) {
    f16 pk[4];
#pragma unroll
    for (int j = 0; j < 4; j++) pk[j] = (f16)((const float*)&v[j])[i];
    *(f16x2*)&T[hwr + i][cr]     = f16x2{pk[0], pk[1]};
    *(f16x2*)&T[hwr + i][cr + 2] = f16x2{pk[2], pk[3]};
  }
  __syncthreads();

  const int hwo = tid >> 2;             // 0..63
  const int cb  = (tid & 3) * 16;       // 0,16,32,48
  f16* dst = xh + ((size_t)b * HW_ + hw0 + hwo) * 512 + c0 + cb;
  *(f16x8*)(dst)     = *(const f16x8*)&T[hwo][cb];
  *(f16x8*)(dst + 8) = *(const f16x8*)&T[hwo][cb + 8];
}

// ---------------- K1: f16 MFMA GEMM  C[spatial,768] = xh · W_all^T ----------------
// 128x128 tile, BK=64, 4 waves x (64x64), global_load_lds(16B) staging with
// XOR slot-swizzle (pre-swizzled global source, swizzled frag reads).
// N-tiles 0,1 -> store t (f16); N-tiles 2..5 -> att epilogue (p/g interleaved cols).
__global__ __launch_bounds__(256) void k_gemm(
    const f16* __restrict__ xh, const f16* __restrict__ wall,
    f16* __restrict__ tbuf, float* __restrict__ att, int bchunk)
{
  __shared__ f16 As[128 * 64];
  __shared__ f16 Bs[128 * 64];

  const int tid = threadIdx.x;
  // XCD-chunked swizzle: 768 blocks = 8 XCD chunks of 96
  const int bid = blockIdx.x;
  const int logical = (bid & 7) * 96 + (bid >> 3);
  const int nt = logical % 6;
  const int mt = (logical / 6) & 31;
  const int bl = logical / 192;          // chunk-local batch 0..3
  const int M0 = mt * 128;
  const int N0 = nt * 128;

  const int l  = tid & 63;
  const int w  = tid >> 6;
  const int wy = w >> 1, wx = w & 1;

  const f16* xb = xh + (size_t)bl * HW_ * 512;

  f32x4 acc[4][4] = {};

  const int srow  = tid >> 3;            // 0..31 (+32i)
  const int sslot = tid & 7;
  const unsigned ldsW = (unsigned)(w * 1024);   // wave-uniform byte offset

  for (int k0 = 0; k0 < 512; k0 += 64) {
    __syncthreads();   // all waves done reading previous chunk
#pragma unroll
    for (int i = 0; i < 4; i++) {
      const int r  = srow + i * 32;
      const int sl = sslot ^ (r & 7);
      const f16* ga = xb + (size_t)(M0 + r) * 512 + k0 + sl * 8;
      __builtin_amdgcn_global_load_lds(
          (const __attribute__((address_space(1))) void*)ga,
          (__attribute__((address_space(3))) void*)((char*)As + i * 4096 + ldsW),
          16, 0, 0);
      const f16* gb = wall + (size_t)(N0 + r) * 512 + k0 + sl * 8;
      __builtin_amdgcn_global_load_lds(
          (const __attribute__((address_space(1))) void*)gb,
          (__attribute__((address_space(3))) void*)((char*)Bs + i * 4096 + ldsW),
          16, 0, 0);
    }
    __syncthreads();   // compiler drains vmcnt before barrier -> data landed

#pragma unroll
    for (int ks = 0; ks < 2; ks++) {
      f16x8 af[4], bf[4];
#pragma unroll
      for (int f = 0; f < 4; f++) {
        const int ra = wy * 64 + f * 16 + (l & 15);
        const int sa = (ks * 4 + (l >> 4)) ^ (ra & 7);
        af[f] = *(const f16x8*)&As[ra * 64 + sa * 8];
        const int rb = wx * 64 + f * 16 + (l & 15);
        const int sb = (ks * 4 + (l >> 4)) ^ (rb & 7);
        bf[f] = *(const f16x8*)&Bs[rb * 64 + sb * 8];
      }
#pragma unroll
      for (int fi = 0; fi < 4; fi++)
#pragma unroll
        for (int fj = 0; fj < 4; fj++)
          acc[fi][fj] = __builtin_amdgcn_mfma_f32_16x16x32_f16(
              af[fi], bf[fj], acc[fi][fj], 0, 0, 0);
    }
  }

  const int bg = bchunk + bl;
  if (N0 < 256) {
    // t tile -> t_t[b][hw][cp] f16
    f16* tb = tbuf + (size_t)bg * HW_ * 256;
#pragma unroll
    for (int fi = 0; fi < 4; fi++) {
      const int hwr = M0 + wy * 64 + fi * 16 + (l >> 4) * 4;
#pragma unroll
      for (int fj = 0; fj < 4; fj++) {
        const int c = N0 + wx * 64 + fj * 16 + (l & 15);
#pragma unroll
        for (int r = 0; r < 4; r++)
          tb[(size_t)(hwr + r) * 256 + c] = (f16)acc[fi][fj][r];
      }
    }
  } else {
    // interleaved p/g columns: pair product via shfl_xor(.,1)
    float s = 0.f;
#pragma unroll
    for (int fi = 0; fi < 4; fi++)
#pragma unroll
      for (int fj = 0; fj < 4; fj++)
#pragma unroll
        for (int r = 0; r < 4; r++) {
          const float v = acc[fi][fj][r];
          s += v * __shfl_xor(v, 1);
        }
#pragma unroll
    for (int off = 32; off > 0; off >>= 1) s += __shfl_xor(s, off);
    if (l == 0) {
      const int grp = (N0 + wx * 64 - 256) >> 6;   // 64 cols per group
      atomicAdd(&att[bg * G_ + grp], 0.5f * s);
    }
  }
}

// ---------------- K2: GroupNorm stats of u = Wz * t ----------------
__global__ __launch_bounds__(256) void k_stats(
    const f16* __restrict__ tbuf, const f16* __restrict__ wzh,
    float* __restrict__ stats)
{
  __shared__ f16x2 wzs[64 * 16];
  __shared__ float red[8];
  const int tid = threadIdx.x;
  const int n0 = blockIdx.x * 1024;
  const int g  = blockIdx.y;
  const int b  = blockIdx.z;

  ((uint4*)wzs)[tid] = ((const uint4*)(wzh + (size_t)g * 2048))[tid];
  __syncthreads();

  const f16* tb = tbuf + ((size_t)b * HW_ + n0 + tid * 4) * 256 + g * 32;
  f16x8 tv[4][4];
#pragma unroll
  for (int j = 0; j < 4; j++)
#pragma unroll
    for (int q = 0; q < 4; q++)
      tv[j][q] = *(const f16x8*)(tb + (size_t)j * 256 + q * 8);

  float s1 = 0.f, s2 = 0.f;
#pragma unroll 2
  for (int o = 0; o < 64; o++) {
    float u[4] = {0.f, 0.f, 0.f, 0.f};
#pragma unroll
    for (int q = 0; q < 4; q++) {
#pragma unroll
      for (int e = 0; e < 4; e++) {
        const f16x2 wz2 = wzs[o * 16 + q * 4 + e];
#pragma unroll
        for (int j = 0; j < 4; j++) {
          const f16x2 t2 = {tv[j][q][2 * e], tv[j][q][2 * e + 1]};
          u[j] = dot2acc(wz2, t2, u[j]);
        }
      }
    }
#pragma unroll
    for (int j = 0; j < 4; j++) {
      s1 += u[j];
      s2 = fmaf(u[j], u[j], s2);
    }
  }
#pragma unroll
  for (int off = 32; off > 0; off >>= 1) {
    s1 += __shfl_xor(s1, off);
    s2 += __shfl_xor(s2, off);
  }
  if ((tid & 63) == 0) { red[(tid >> 6) * 2] = s1; red[(tid >> 6) * 2 + 1] = s2; }
  __syncthreads();
  if (tid == 0) {
    atomicAdd(&stats[(b * G_ + g) * 2 + 0], red[0] + red[2] + red[4] + red[6]);
    atomicAdd(&stats[(b * G_ + g) * 2 + 1], red[1] + red[3] + red[5] + red[7]);
  }
}

// ---------------- K3: recompute u, apply att/GroupNorm/residual ----------------
__global__ __launch_bounds__(256) void k_out(
    const f16* __restrict__ tbuf, const f16* __restrict__ wzh,
    const float* __restrict__ x, const float* __restrict__ gamma,
    const float* __restrict__ beta, const float* __restrict__ att,
    const float* __restrict__ stats, float* __restrict__ out)
{
  __shared__ f16x2 wzs[64 * 16];
  const int tid = threadIdx.x;
  const int n0 = blockIdx.x * 1024;
  const int g  = blockIdx.y;
  const int b  = blockIdx.z;

  ((uint4*)wzs)[tid] = ((const uint4*)(wzh + (size_t)g * 2048))[tid];
  __syncthreads();

  const f16* tb = tbuf + ((size_t)b * HW_ + n0 + tid * 4) * 256 + g * 32;
  f16x8 tv[4][4];
#pragma unroll
  for (int j = 0; j < 4; j++)
#pragma unroll
    for (int q = 0; q < 4; q++)
      tv[j][q] = *(const f16x8*)(tb + (size_t)j * 256 + q * 8);

  const float attv = att[b * G_ + g];
  const float invN = 1.f / (64.f * 4096.f);
  const float S1 = stats[(b * G_ + g) * 2 + 0];
  const float S2 = stats[(b * G_ + g) * 2 + 1];
  const float mu  = S1 * invN;
  const float var = S2 * invN - mu * mu;
  const float sc  = attv * rsqrtf(attv * attv * var + EPS_);

#pragma unroll 2
  for (int o = 0; o < 64; o++) {
    float u[4] = {0.f, 0.f, 0.f, 0.f};
#pragma unroll
    for (int q = 0; q < 4; q++) {
#pragma unroll
      for (int e = 0; e < 4; e++) {
        const f16x2 wz2 = wzs[o * 16 + q * 4 + e];
#pragma unroll
        for (int j = 0; j < 4; j++) {
          const f16x2 t2 = {tv[j][q][2 * e], tv[j][q][2 * e + 1]};
          u[j] = dot2acc(wz2, t2, u[j]);
        }
      }
    }
    const int c = g * 64 + o;
    const float gm = gamma[c];
    const float bt = beta[c];
    const size_t off = ((size_t)b * CIN_ + c) * HW_ + n0 + tid * 4;
    const float4 xv = *(const float4*)(x + off);
    float4 ov;
    ov.x = fmaf((u[0] - mu) * sc, gm, bt + xv.x);
    ov.y = fmaf((u[1] - mu) * sc, gm, bt + xv.y);
    ov.z = fmaf((u[2] - mu) * sc, gm, bt + xv.z);
    ov.w = fmaf((u[3] - mu) * sc, gm, bt + xv.w);
    *(float4*)(out + off) = ov;
  }
}

extern "C" void kernel_launch(void* const* d_in, const int* in_sizes, int n_in,
                              void* d_out, int out_size, void* d_ws, size_t ws_size,
                              hipStream_t stream)
{
  const float* x     = (const float*)d_in[0];
  const float* Wt    = (const float*)d_in[1];
  const float* Wp    = (const float*)d_in[2];
  const float* Wg    = (const float*)d_in[3];
  const float* Wz    = (const float*)d_in[4];
  const float* gamma = (const float*)d_in[5];
  const float* beta  = (const float*)d_in[6];
  float* out = (float*)d_out;

  char* ws = (char*)d_ws;
  f16*   wall  = (f16*)(ws + OFF_WALL);
  f16*   wzh   = (f16*)(ws + OFF_WZH);
  float* att   = (float*)(ws + OFF_ATT);
  float* stats = (float*)(ws + OFF_STATS);
  f16*   tbuf  = (f16*)(ws + OFF_T);
  f16*   xh    = (f16*)(ws + OFF_XH);

  k_prep0<<<1602, 256, 0, stream>>>(Wt, Wp, Wg, Wz, ws);

  for (int cb = 0; cb < 4; cb++) {
    dim3 gx(8, 64, 4);   // c-tiles, hw-tiles, chunk-local batch
    k_xpose<<<gx, 256, 0, stream>>>(x + (size_t)cb * 4 * CIN_ * HW_, xh);
    k_gemm<<<768, 256, 0, stream>>>(xh, wall, tbuf, att, cb * 4);
  }

  dim3 g2(4, G_, B_);
  k_stats<<<g2, 256, 0, stream>>>(tbuf, wzh, stats);
  k_out<<<g2, 256, 0, stream>>>(tbuf, wzh, x, gamma, beta, att, stats, out);
}

// Round 6
// 394.832 us; speedup vs baseline: 2.2321x; 1.1562x over previous
//
#include <hip/hip_runtime.h>
#include <stddef.h>
#include <stdint.h>

#define B_   16
#define CIN_ 512
#define HW_  4096
#define CP_  256
#define G_   8
#define EPS_ 1e-5f

typedef _Float16 f16;
typedef _Float16 f16x8 __attribute__((ext_vector_type(8)));
typedef _Float16 f16x2 __attribute__((ext_vector_type(2)));
typedef float    f32x4 __attribute__((ext_vector_type(4)));

// ---- workspace layout (bytes); ws proven >= 512 MiB (fill WRITE_SIZE). total used ~101.7 MiB
#define OFF_WALL   0u          // W_all f16 [768][512]          = 786432 B
#define OFF_WZH    786432u     // Wzh  f16 [8][64][32]          =  32768 B
#define OFF_ATT    819200u     // att  f32 [128]                =    512 B
#define OFF_STATS  819712u     // stats f32 [256]               =   1024 B
#define OFF_T      1048576u    // t_t  f16 [16][4096][256]      = 33554432 B
#define OFF_XH     34603008u   // xh   f16 [16][4096][512]      = 67108864 B (end 101.7MB)

#if defined(__has_builtin)
#if __has_builtin(__builtin_amdgcn_fdot2)
#define HAVE_FDOT2 1
#endif
#endif

__device__ __forceinline__ float dot2acc(f16x2 a, f16x2 b, float c) {
#ifdef HAVE_FDOT2
  return __builtin_amdgcn_fdot2(a, b, c, false);
#else
  return fmaf((float)a[0], (float)b[0], fmaf((float)a[1], (float)b[1], c));
#endif
}

// ---------------- K0: build W_all (t rows plain, p/g rows interleaved),
// Wzh f16, zero att+stats ----------------
__global__ __launch_bounds__(256) void k_prep0(
    const float* __restrict__ Wt, const float* __restrict__ Wp,
    const float* __restrict__ Wg, const float* __restrict__ Wz,
    char* __restrict__ ws)
{
  f16*   wall  = (f16*)(ws + OFF_WALL);
  f16*   wzh   = (f16*)(ws + OFF_WZH);
  float* att   = (float*)(ws + OFF_ATT);
  int idx = blockIdx.x * 256 + threadIdx.x;
  if (idx < 768 * 512) {
    int r = idx >> 9, k = idx & 511;
    float v;
    if (r < 256) v = Wt[r * 512 + k];
    else {
      int q = r - 256, o = q >> 1;
      v = (q & 1) ? Wg[o * 512 + k] : Wp[o * 512 + k];
    }
    wall[idx] = (f16)v;
  } else if (idx < 768 * 512 + 16384) {
    int i = idx - 768 * 512;
    wzh[i] = (f16)Wz[i];
  } else if (idx < 768 * 512 + 16384 + 384) {
    att[idx - (768 * 512 + 16384)] = 0.f;   // covers att(128) + stats(256)
  }
}

// ---------------- K_xpose: x[b][c][hw] f32 -> xh[b][hw][c] f16 (all 16 batches) ----------------
__global__ __launch_bounds__(256) void k_xpose(const float* __restrict__ x,
                                               f16* __restrict__ xh)
{
  __shared__ f16 T[64][72];
  const int tid = threadIdx.x;
  const int c0  = blockIdx.x * 64;
  const int hw0 = blockIdx.y * 64;
  const int b   = blockIdx.z;

  const int cr  = (tid >> 4) * 4;       // 0..60, 4 consecutive c rows
  const int hwr = (tid & 15) * 4;       // 0..60
  const float* xb = x + ((size_t)b * CIN_ + c0) * HW_ + hw0;

  float4 v[4];
#pragma unroll
  for (int j = 0; j < 4; j++)
    v[j] = *(const float4*)(xb + (size_t)(cr + j) * HW_ + hwr);

#pragma unroll
  for (int i = 0; i < 4; i++) {
    f16 pk[4];
#pragma unroll
    for (int j = 0; j < 4; j++) pk[j] = (f16)((const float*)&v[j])[i];
    *(f16x2*)&T[hwr + i][cr]     = f16x2{pk[0], pk[1]};
    *(f16x2*)&T[hwr + i][cr + 2] = f16x2{pk[2], pk[3]};
  }
  __syncthreads();

  const int hwo = tid >> 2;             // 0..63
  const int cb  = (tid & 3) * 16;       // 0,16,32,48
  f16* dst = xh + ((size_t)b * HW_ + hw0 + hwo) * 512 + c0 + cb;
  *(f16x8*)(dst)     = *(const f16x8*)&T[hwo][cb];
  *(f16x8*)(dst + 8) = *(const f16x8*)&T[hwo][cb + 8];
}

// ---------------- K1: f16 MFMA GEMM  C[spatial,768] = xh · W_all^T ----------------
// Single launch, 3072 blocks (12/CU queue depth). 128x128 tile, BK=64, 4 waves.
// global_load_lds(16B) staging, XOR slot-swizzle (pre-swizzled source + swizzled read).
// Epilogue: t quadrants bounced through LDS -> f16x8 coalesced stores;
// p/g interleaved columns reduced to att via shfl_xor(.,1).
__global__ __launch_bounds__(256) void k_gemm(
    const f16* __restrict__ xh, const f16* __restrict__ wall,
    f16* __restrict__ tbuf, float* __restrict__ att)
{
  __shared__ union SM {
    struct { f16 A[128 * 64]; f16 B[128 * 64]; } s;   // 32 KiB staging
    f16 ep[4][64 * 72];                               // 36 KiB epilogue bounce
  } sm;

  const int tid = threadIdx.x;
  // XCD-chunked swizzle: 3072 = 8 XCDs x 384; nt fastest so the 6 N-tiles
  // sharing an A-panel land on one XCD's L2. Bijective (3072 = 6*32*16).
  const int bid = blockIdx.x;
  const int logical = (bid & 7) * 384 + (bid >> 3);
  const int nt   = logical % 6;
  const int rest = logical / 6;          // 0..511
  const int mt   = rest & 31;
  const int bl   = rest >> 5;            // batch 0..15
  const int M0 = mt * 128;
  const int N0 = nt * 128;

  const int l  = tid & 63;
  const int w  = tid >> 6;
  const int wy = w >> 1, wx = w & 1;

  const f16* xb = xh + (size_t)bl * HW_ * 512;

  f32x4 acc[4][4] = {};

  const int srow  = tid >> 3;            // 0..31 (+32i)
  const int sslot = tid & 7;
  const unsigned ldsW = (unsigned)(w * 1024);   // wave-uniform byte offset

  for (int k0 = 0; k0 < 512; k0 += 64) {
    __syncthreads();   // all waves done reading previous chunk
#pragma unroll
    for (int i = 0; i < 4; i++) {
      const int r  = srow + i * 32;
      const int sl = sslot ^ (r & 7);
      const f16* ga = xb + (size_t)(M0 + r) * 512 + k0 + sl * 8;
      __builtin_amdgcn_global_load_lds(
          (const __attribute__((address_space(1))) void*)ga,
          (__attribute__((address_space(3))) void*)((char*)sm.s.A + i * 4096 + ldsW),
          16, 0, 0);
      const f16* gb = wall + (size_t)(N0 + r) * 512 + k0 + sl * 8;
      __builtin_amdgcn_global_load_lds(
          (const __attribute__((address_space(1))) void*)gb,
          (__attribute__((address_space(3))) void*)((char*)sm.s.B + i * 4096 + ldsW),
          16, 0, 0);
    }
    __syncthreads();   // compiler drains vmcnt before barrier -> data landed

#pragma unroll
    for (int ks = 0; ks < 2; ks++) {
      f16x8 af[4], bf[4];
#pragma unroll
      for (int f = 0; f < 4; f++) {
        const int ra = wy * 64 + f * 16 + (l & 15);
        const int sa = (ks * 4 + (l >> 4)) ^ (ra & 7);
        af[f] = *(const f16x8*)&sm.s.A[ra * 64 + sa * 8];
        const int rb = wx * 64 + f * 16 + (l & 15);
        const int sb = (ks * 4 + (l >> 4)) ^ (rb & 7);
        bf[f] = *(const f16x8*)&sm.s.B[rb * 64 + sb * 8];
      }
#pragma unroll
      for (int fi = 0; fi < 4; fi++)
#pragma unroll
        for (int fj = 0; fj < 4; fj++)
          acc[fi][fj] = __builtin_amdgcn_mfma_f32_16x16x32_f16(
              af[fi], bf[fj], acc[fi][fj], 0, 0, 0);
    }
  }

  __syncthreads();   // staging LDS dead; epilogue may overwrite (block-uniform)

  if (N0 < 256) {
    // stage this wave's 64x64 quadrant in LDS (stride 72 f16 = 144B, 16B-aligned)
    f16* ep = sm.ep[w];
#pragma unroll
    for (int fi = 0; fi < 4; fi++)
#pragma unroll
      for (int fj = 0; fj < 4; fj++)
#pragma unroll
        for (int r = 0; r < 4; r++)
          ep[(fi * 16 + (l >> 4) * 4 + r) * 72 + fj * 16 + (l & 15)] =
              (f16)acc[fi][fj][r];
    // wave-private region: in-wave lgkmcnt ordering suffices, no barrier
    f16* tb = tbuf + (size_t)bl * HW_ * 256;
    const int hwb = M0 + wy * 64;
    const int cb2 = N0 + wx * 64;
#pragma unroll
    for (int q = 0; q < 8; q++) {
      const int row = q * 8 + (l >> 3);
      const int cc  = (l & 7) * 8;
      *(f16x8*)&tb[(size_t)(hwb + row) * 256 + cb2 + cc] =
          *(const f16x8*)&ep[row * 72 + cc];
    }
  } else {
    // interleaved p/g columns: pair product via shfl_xor(.,1)
    float s = 0.f;
#pragma unroll
    for (int fi = 0; fi < 4; fi++)
#pragma unroll
      for (int fj = 0; fj < 4; fj++)
#pragma unroll
        for (int r = 0; r < 4; r++) {
          const float v = acc[fi][fj][r];
          s += v * __shfl_xor(v, 1);
        }
#pragma unroll
    for (int off = 32; off > 0; off >>= 1) s += __shfl_xor(s, off);
    if (l == 0) {
      const int grp = (N0 + wx * 64 - 256) >> 6;   // 64 cols per group
      atomicAdd(&att[bl * G_ + grp], 0.5f * s);
    }
  }
}

// ---------------- K2: GroupNorm stats of u = Wz * t ----------------
__global__ __launch_bounds__(256) void k_stats(
    const f16* __restrict__ tbuf, const f16* __restrict__ wzh,
    float* __restrict__ stats)
{
  __shared__ f16x2 wzs[64 * 16];
  __shared__ float red[8];
  const int tid = threadIdx.x;
  const int n0 = blockIdx.x * 1024;
  const int g  = blockIdx.y;
  const int b  = blockIdx.z;

  ((uint4*)wzs)[tid] = ((const uint4*)(wzh + (size_t)g * 2048))[tid];
  __syncthreads();

  const f16* tb = tbuf + ((size_t)b * HW_ + n0 + tid * 4) * 256 + g * 32;
  f16x8 tv[4][4];
#pragma unroll
  for (int j = 0; j < 4; j++)
#pragma unroll
    for (int q = 0; q < 4; q++)
      tv[j][q] = *(const f16x8*)(tb + (size_t)j * 256 + q * 8);

  float s1 = 0.f, s2 = 0.f;
#pragma unroll 2
  for (int o = 0; o < 64; o++) {
    float u[4] = {0.f, 0.f, 0.f, 0.f};
#pragma unroll
    for (int q = 0; q < 4; q++) {
#pragma unroll
      for (int e = 0; e < 4; e++) {
        const f16x2 wz2 = wzs[o * 16 + q * 4 + e];
#pragma unroll
        for (int j = 0; j < 4; j++) {
          const f16x2 t2 = {tv[j][q][2 * e], tv[j][q][2 * e + 1]};
          u[j] = dot2acc(wz2, t2, u[j]);
        }
      }
    }
#pragma unroll
    for (int j = 0; j < 4; j++) {
      s1 += u[j];
      s2 = fmaf(u[j], u[j], s2);
    }
  }
#pragma unroll
  for (int off = 32; off > 0; off >>= 1) {
    s1 += __shfl_xor(s1, off);
    s2 += __shfl_xor(s2, off);
  }
  if ((tid & 63) == 0) { red[(tid >> 6) * 2] = s1; red[(tid >> 6) * 2 + 1] = s2; }
  __syncthreads();
  if (tid == 0) {
    atomicAdd(&stats[(b * G_ + g) * 2 + 0], red[0] + red[2] + red[4] + red[6]);
    atomicAdd(&stats[(b * G_ + g) * 2 + 1], red[1] + red[3] + red[5] + red[7]);
  }
}

// ---------------- K3: recompute u, apply att/GroupNorm/residual ----------------
__global__ __launch_bounds__(256) void k_out(
    const f16* __restrict__ tbuf, const f16* __restrict__ wzh,
    const float* __restrict__ x, const float* __restrict__ gamma,
    const float* __restrict__ beta, const float* __restrict__ att,
    const float* __restrict__ stats, float* __restrict__ out)
{
  __shared__ f16x2 wzs[64 * 16];
  const int tid = threadIdx.x;
  const int n0 = blockIdx.x * 1024;
  const int g  = blockIdx.y;
  const int b  = blockIdx.z;

  ((uint4*)wzs)[tid] = ((const uint4*)(wzh + (size_t)g * 2048))[tid];
  __syncthreads();

  const f16* tb = tbuf + ((size_t)b * HW_ + n0 + tid * 4) * 256 + g * 32;
  f16x8 tv[4][4];
#pragma unroll
  for (int j = 0; j < 4; j++)
#pragma unroll
    for (int q = 0; q < 4; q++)
      tv[j][q] = *(const f16x8*)(tb + (size_t)j * 256 + q * 8);

  const float attv = att[b * G_ + g];
  const float invN = 1.f / (64.f * 4096.f);
  const float S1 = stats[(b * G_ + g) * 2 + 0];
  const float S2 = stats[(b * G_ + g) * 2 + 1];
  const float mu  = S1 * invN;
  const float var = S2 * invN - mu * mu;
  const float sc  = attv * rsqrtf(attv * attv * var + EPS_);

#pragma unroll 2
  for (int o = 0; o < 64; o++) {
    float u[4] = {0.f, 0.f, 0.f, 0.f};
#pragma unroll
    for (int q = 0; q < 4; q++) {
#pragma unroll
      for (int e = 0; e < 4; e++) {
        const f16x2 wz2 = wzs[o * 16 + q * 4 + e];
#pragma unroll
        for (int j = 0; j < 4; j++) {
          const f16x2 t2 = {tv[j][q][2 * e], tv[j][q][2 * e + 1]};
          u[j] = dot2acc(wz2, t2, u[j]);
        }
      }
    }
    const int c = g * 64 + o;
    const float gm = gamma[c];
    const float bt = beta[c];
    const size_t off = ((size_t)b * CIN_ + c) * HW_ + n0 + tid * 4;
    const float4 xv = *(const float4*)(x + off);
    float4 ov;
    ov.x = fmaf((u[0] - mu) * sc, gm, bt + xv.x);
    ov.y = fmaf((u[1] - mu) * sc, gm, bt + xv.y);
    ov.z = fmaf((u[2] - mu) * sc, gm, bt + xv.z);
    ov.w = fmaf((u[3] - mu) * sc, gm, bt + xv.w);
    *(float4*)(out + off) = ov;
  }
}

extern "C" void kernel_launch(void* const* d_in, const int* in_sizes, int n_in,
                              void* d_out, int out_size, void* d_ws, size_t ws_size,
                              hipStream_t stream)
{
  const float* x     = (const float*)d_in[0];
  const float* Wt    = (const float*)d_in[1];
  const float* Wp    = (const float*)d_in[2];
  const float* Wg    = (const float*)d_in[3];
  const float* Wz    = (const float*)d_in[4];
  const float* gamma = (const float*)d_in[5];
  const float* beta  = (const float*)d_in[6];
  float* out = (float*)d_out;

  char* ws = (char*)d_ws;
  f16*   wall  = (f16*)(ws + OFF_WALL);
  f16*   wzh   = (f16*)(ws + OFF_WZH);
  float* att   = (float*)(ws + OFF_ATT);
  float* stats = (float*)(ws + OFF_STATS);
  f16*   tbuf  = (f16*)(ws + OFF_T);
  f16*   xh    = (f16*)(ws + OFF_XH);

  k_prep0<<<1602, 256, 0, stream>>>(Wt, Wp, Wg, Wz, ws);

  dim3 gx(8, 64, 16);
  k_xpose<<<gx, 256, 0, stream>>>(x, xh);
  k_gemm<<<3072, 256, 0, stream>>>(xh, wall, tbuf, att);

  dim3 g2(4, G_, B_);
  k_stats<<<g2, 256, 0, stream>>>(tbuf, wzh, stats);
  k_out<<<g2, 256, 0, stream>>>(tbuf, wzh, x, gamma, beta, att, stats, out);
}